// Round 3
// baseline (160.980 us; speedup 1.0000x reference)
//
#include <hip/hip_runtime.h>
#include <hip/hip_bf16.h>

// BatchedNLM: per-neuron 2-layer GLU MLP.
//   state_trace (128,2048,32) f32, fc1_w (2048,32,256), fc1_b (2048,256),
//   fc2_w (2048,128,2), fc2_b (2048,2), T (1)  ->  out (128,2048) f32
//
// R9: 4 neurons per block (grid 512), 512 threads = 8 waves; wave w owns
// batches [16w,16w+16). Double-buffered w1 staging + raw s_barrier with
// counted waitcnts so the next neuron's DMA stays in flight across the
// current neuron's conv/compute barriers (vmcnt(0) only at iteration end,
// covered by ~1500 cyc of work). GEMM1 via mfma_f32_16x16x32_bf16.
// GLU1 pairs (h,h+128) = tiles (p,p+8) register-only; fc2 folded as
// per-lane partials + shfl_xor tree.
//
// History:
// R4/R7 FAILED: register-staging w1 spills (R7: 113 MB scratch writes).
// R5 WIN: w1 via global_load_lds width=16 (async DMA, no VGPRs).
// R6 (~40us): rcp-sigmoid + bf16 buffer aliased into f32 staging.
// R8 NEUTRAL (41.4us): 512 thr/block doubled theoretical occupancy -> no
//     change. Counters: FETCH 51MB, HBM 16%, VALU 32%, Mfma 3.6%, Occ 30%.
//     Lesson: not a capacity problem; the serial per-block chain
//     (DMA -> __syncthreads vmcnt(0) drain -> conv -> compute) exposes full
//     memory latency every block. -> R9 pipelines neurons.

#define NN 2048
#define NPB 4            // neurons per block
#define GRID (NN / NPB)  // 512

typedef __attribute__((ext_vector_type(8))) short short8;
typedef __attribute__((ext_vector_type(4))) float floatx4;
typedef __attribute__((ext_vector_type(4))) int int4v;

static __device__ __forceinline__ unsigned int pkbf(float a, float b) {
    __hip_bfloat162 h = __float22bfloat162_rn(make_float2(a, b));  // v_cvt_pk_bf16_f32
    return *(unsigned int*)&h;
}

static __device__ __forceinline__ float sigmoidf_(float x) {
    return __builtin_amdgcn_rcpf(1.0f + __expf(-x));  // mul+exp+add+rcp
}

static __device__ __forceinline__ void gload_lds16(const float* g, float* l) {
    // Per-lane gptr; LDS dest = wave-uniform base + lane*16B (m97/m104 semantics).
    __builtin_amdgcn_global_load_lds((const __attribute__((address_space(1))) void*)g,
                                     (__attribute__((address_space(3))) void*)l,
                                     16, 0, 0);
}

static __device__ __forceinline__ short8 pack_afrag(floatx4 a0, floatx4 a1) {
    union { int4v i; short8 s; } u;
    u.i[0] = pkbf(a0[0], a0[1]);
    u.i[1] = pkbf(a0[2], a0[3]);
    u.i[2] = pkbf(a1[0], a1[1]);
    u.i[3] = pkbf(a1[2], a1[3]);
    return u.s;
}

__global__ __launch_bounds__(512, 4)
void nlm_kernel(const float* __restrict__ st,
                const float* __restrict__ w1,
                const float* __restrict__ b1,
                const float* __restrict__ w2,
                const float* __restrict__ b2,
                const float* __restrict__ Tp,
                float* __restrict__ out_t)
{
    const int t  = threadIdx.x;          // 0..511
    const int n0 = blockIdx.x * NPB;

    // Two 32 KB f32 staging buffers; the CURRENT one's first 16 KB is reused
    // as the fragment-major bf16 buffer after the conv-read barrier.
    __shared__ __align__(16) float  ldsW[2][32 * 256];   // 64 KB
    __shared__ float4 ldsP[2][128];                      // 4 KB params dbuf
    __shared__ float  ldsO[128];                         // out row

    const int lane = t & 63;
    const int wv   = t >> 6;      // wave 0..7
    const int m    = lane & 15;   // A row / C col
    const int quad = lane >> 4;   // k-quad / C row group

    const int h      = t & 255;        // conv: owned column
    const int kh     = t >> 8;         // conv: k-half 0/1
    // fragment-major short idx = (h>>4)*512 + (k>>3)*128 + (h&15)*8 + (k&7)
    const int cvbase = ((h >> 4) * 512) + ((h & 15) * 8) + kh * 256;

    // ---------------- prologue: neuron n0 ----------------
    float pba = 0.f, pbb = 0.f; float2 pw2 = make_float2(0.f, 0.f);
    if (t < 128) {
        pba = b1[(size_t)n0 * 256 + t];
        pbb = b1[(size_t)n0 * 256 + 128 + t];
        pw2 = *(const float2*)(w2 + (size_t)n0 * 256 + 2 * t);
    }
    floatx4 av0, av1;
    {
        const int b = wv * 16 + m;
        const float* sp = st + (size_t)b * (NN * 32) + (size_t)n0 * 32 + quad * 8;
        av0 = *(const floatx4*)sp;
        av1 = *(const floatx4*)(sp + 4);
    }
    {
        const float* gW = w1 + (size_t)n0 * 8192;
        #pragma unroll
        for (int i2 = 0; i2 < 4; ++i2) {
            const int off = wv * 1024 + i2 * 256;
            gload_lds16(gW + off + lane * 4, &ldsW[0][off]);
        }
    }
    float bb0 = b2[n0 * 2 + 0];
    float bb1 = b2[n0 * 2 + 1];
    const float invT = 1.0f / Tp[0];
    if (t < 128) ldsP[0][t] = make_float4(pba, pbb, pw2.x, pw2.y);
    short8 afrag = pack_afrag(av0, av1);

    __syncthreads();   // prologue full drain: buf0 + ldsP[0] ready

    #pragma unroll
    for (int i = 0; i < NPB; ++i) {
        const int cur = i & 1, nxt = cur ^ 1;
        const int n = n0 + i;
        const bool hn = (i + 1 < NPB);
        short* ldsBc = (short*)ldsW[cur];

        // ---- 1) prefetch neuron n+1. Register loads issued BEFORE the DMA
        //         so their counted vmcnt waits don't force a DMA drain. ----
        float npa = 0.f, npb_ = 0.f; float2 npw = make_float2(0.f, 0.f);
        floatx4 nav0 = {0,0,0,0}, nav1 = {0,0,0,0};
        float nbb0 = 0.f, nbb1 = 0.f;
        if (hn) {
            if (t < 128) {
                npa  = b1[(size_t)(n + 1) * 256 + t];
                npb_ = b1[(size_t)(n + 1) * 256 + 128 + t];
                npw  = *(const float2*)(w2 + (size_t)(n + 1) * 256 + 2 * t);
            }
            const int b = wv * 16 + m;
            const float* sp = st + (size_t)b * (NN * 32) + (size_t)(n + 1) * 32 + quad * 8;
            nav0 = *(const floatx4*)sp;
            nav1 = *(const floatx4*)(sp + 4);
            nbb0 = b2[(n + 1) * 2 + 0];
            nbb1 = b2[(n + 1) * 2 + 1];
            const float* gW = w1 + (size_t)(n + 1) * 8192;
            #pragma unroll
            for (int i2 = 0; i2 < 4; ++i2) {
                const int off = wv * 1024 + i2 * 256;
                gload_lds16(gW + off + lane * 4, &ldsW[nxt][off]);
            }
        }

        // ---- 2) conv reads: thread owns column h, k-half kh (16 b32, free) ----
        float w[16];
        #pragma unroll
        for (int k = 0; k < 16; ++k)
            w[k] = ldsW[cur][(kh * 16 + k) * 256 + h];

        // ---- 3) barrier: all f32 reads done before bf16 overwrite.
        //         lgkm only — DMA (vmcnt) stays in flight. ----
        asm volatile("s_waitcnt lgkmcnt(0)" ::: "memory");
        __builtin_amdgcn_s_barrier();
        __builtin_amdgcn_sched_barrier(0);

        // ---- 4) bf16 fragment-major writes into ldsBc; pack next afrag ----
        #pragma unroll
        for (int q = 0; q < 2; ++q) {
            union { int4v iv; short8 s; } u;
            #pragma unroll
            for (int e = 0; e < 4; ++e)
                u.iv[e] = pkbf(w[q * 8 + 2 * e], w[q * 8 + 2 * e + 1]);
            *(short8*)&ldsBc[cvbase + q * 128] = u.s;
        }
        short8 nafrag = afrag;
        if (hn) nafrag = pack_afrag(nav0, nav1);

        // ---- 5) barrier: bf16 visible before compute reads ----
        asm volatile("s_waitcnt lgkmcnt(0)" ::: "memory");
        __builtin_amdgcn_s_barrier();
        __builtin_amdgcn_sched_barrier(0);

        // ---- 6) compute: 8 tile-pairs, fc1 bias as MFMA C-init, fc2 folded ----
        float pacc[4][2];
        #pragma unroll
        for (int r = 0; r < 4; ++r)
            pacc[r][0] = pacc[r][1] = 0.0f;

        #pragma unroll
        for (int p = 0; p < 8; ++p) {
            short8 bfA = *(short8*)&ldsBc[(p * 64 + lane) * 8];
            short8 bfB = *(short8*)&ldsBc[((p + 8) * 64 + lane) * 8];
            float4 prm = ldsP[cur][p * 16 + m];
            floatx4 ca = {prm.x, prm.x, prm.x, prm.x};
            floatx4 cb = {prm.y, prm.y, prm.y, prm.y};
            floatx4 xa = __builtin_amdgcn_mfma_f32_16x16x32_bf16(afrag, bfA, ca, 0, 0, 0);
            floatx4 xb = __builtin_amdgcn_mfma_f32_16x16x32_bf16(afrag, bfB, cb, 0, 0, 0);
            #pragma unroll
            for (int r = 0; r < 4; ++r) {
                float glu = xa[r] * sigmoidf_(xb[r]);
                pacc[r][0] += glu * prm.z;
                pacc[r][1] += glu * prm.w;
            }
        }

        #pragma unroll
        for (int r = 0; r < 4; ++r) {
            float s0 = pacc[r][0];
            float s1 = pacc[r][1];
            s0 += __shfl_xor(s0, 1);  s1 += __shfl_xor(s1, 1);
            s0 += __shfl_xor(s0, 2);  s1 += __shfl_xor(s1, 2);
            s0 += __shfl_xor(s0, 4);  s1 += __shfl_xor(s1, 4);
            s0 += __shfl_xor(s0, 8);  s1 += __shfl_xor(s1, 8);
            if (m == 0) {
                const int b = wv * 16 + quad * 4 + r;
                float x0 = s0 + bb0;
                float x1 = s1 + bb1;
                ldsO[b] = x0 * sigmoidf_(x1) * invT;
            }
        }
        // next-neuron params into the other ldsP buffer (its readers finished
        // at the previous iteration's end barrier)
        if (hn && t < 128)
            ldsP[nxt][t] = make_float4(npa, npb_, npw.x, npw.y);

        // ---- 7) iteration-end barrier: drain the prefetch DMA (covered by
        //         all of conv+compute above) + ldsO/ldsP writes ----
        asm volatile("s_waitcnt vmcnt(0) lgkmcnt(0)" ::: "memory");
        __builtin_amdgcn_s_barrier();
        __builtin_amdgcn_sched_barrier(0);

        // coalesced 512B row for neuron n
        if (t < 128)
            out_t[(size_t)n * 128 + t] = ldsO[t];

        afrag = nafrag;
        bb0 = nbb0;
        bb1 = nbb1;
    }
}

// Transpose out_t (2048,128) -> out (128,2048). 32x32 tiles, 256 blocks.
__global__ __launch_bounds__(256)
void transpose_kernel(const float* __restrict__ out_t, float* __restrict__ out)
{
    __shared__ float tile[32][33];
    const int t    = threadIdx.x;
    const int bidx = blockIdx.x;           // 0..255
    const int n0   = (bidx & 63) * 32;     // 64 n-tiles
    const int b0   = (bidx >> 6) * 32;     // 4 b-tiles

    const int tx = t & 31;
    const int ty = t >> 5;                 // 0..7

    #pragma unroll
    for (int i = 0; i < 4; ++i) {
        const int nl = ty + i * 8;
        tile[nl][tx] = out_t[(size_t)(n0 + nl) * 128 + b0 + tx];
    }

    __syncthreads();

    #pragma unroll
    for (int i = 0; i < 4; ++i) {
        const int bl = ty + i * 8;
        out[(size_t)(b0 + bl) * NN + n0 + tx] = tile[tx][bl];
    }
}

extern "C" void kernel_launch(void* const* d_in, const int* in_sizes, int n_in,
                              void* d_out, int out_size, void* d_ws, size_t ws_size,
                              hipStream_t stream) {
    const float* st = (const float*)d_in[0];
    const float* w1 = (const float*)d_in[1];
    const float* b1 = (const float*)d_in[2];
    const float* w2 = (const float*)d_in[3];
    const float* b2 = (const float*)d_in[4];
    const float* T  = (const float*)d_in[5];
    float* out   = (float*)d_out;
    float* out_t = (float*)d_ws;    // 2048*128*4 = 1 MB scratch

    nlm_kernel<<<dim3(GRID), dim3(512), 0, stream>>>(st, w1, b1, w2, b2, T, out_t);
    transpose_kernel<<<dim3(256), dim3(256), 0, stream>>>(out_t, out);
}

// Round 4
// 143.073 us; speedup vs baseline: 1.1252x; 1.1252x over previous
//
#include <hip/hip_runtime.h>
#include <hip/hip_bf16.h>

// BatchedNLM: per-neuron 2-layer GLU MLP.
//   state_trace (128,2048,32) f32, fc1_w (2048,32,256), fc1_b (2048,256),
//   fc2_w (2048,128,2), fc2_b (2048,2), T (1)  ->  out (128,2048) f32
//
// R10: 4 neurons per block (grid 512), 512 threads = 8 waves; wave w owns
// batches [16w,16w+16). Pipeline: one 32KB f32 stage S + separate 16KB bf16
// buffer B. Next neuron's w1 DMA is issued the moment S's readers are done
// and drains only at the iteration-end vmcnt(0) barrier (covered by
// bf16-conv + MFMA + GLU work). st/param register prefetches are issued
// BEFORE the DMA so their waits are counted vmcnt(4), never a drain.
// GEMM1 via mfma_f32_16x16x32_bf16, fc1 bias as MFMA C-init; GLU1 pairs
// (h,h+128)=tiles (p,p+8) register-only; fc2 folded as per-lane partials
// + shfl_xor tree.
//
// History:
// R4/R7 FAILED: register-staging w1 spills (R7: 113 MB scratch writes).
// R5 WIN: w1 via global_load_lds width=16 (async DMA, no VGPRs).
// R6 (~40us): rcp-sigmoid + bf16 buffer aliased into f32 staging.
// R8 NEUTRAL (41.4us): 2x theoretical occupancy, no change -> latency-bound
//     serial chain per block, not capacity.
// R9 FAILED (61.7us): pipeline was right but __launch_bounds__(512,4)
//     capped VGPR at 64 (empirical: cap ~ 256/arg in this toolchain) ->
//     38 dwords/thread scratch (WRITE 39 MB). Lesson: declare (512,2).
// R10 (this): (512,2) -> cap 128, no spill; LDS 68.5->52.5 KB (S+B instead
//     of 2xS) -> 3 blocks/CU, entire 512-block grid co-resident.

#define NN 2048
#define NPB 4            // neurons per block
#define GRID (NN / NPB)  // 512

typedef __attribute__((ext_vector_type(8))) short short8;
typedef __attribute__((ext_vector_type(4))) float floatx4;
typedef __attribute__((ext_vector_type(4))) int int4v;

static __device__ __forceinline__ unsigned int pkbf(float a, float b) {
    __hip_bfloat162 h = __float22bfloat162_rn(make_float2(a, b));  // v_cvt_pk_bf16_f32
    return *(unsigned int*)&h;
}

static __device__ __forceinline__ float sigmoidf_(float x) {
    return __builtin_amdgcn_rcpf(1.0f + __expf(-x));  // mul+exp+add+rcp
}

static __device__ __forceinline__ void gload_lds16(const float* g, float* l) {
    // Per-lane gptr; LDS dest = wave-uniform base + lane*16B (m97/m104 semantics).
    __builtin_amdgcn_global_load_lds((const __attribute__((address_space(1))) void*)g,
                                     (__attribute__((address_space(3))) void*)l,
                                     16, 0, 0);
}

static __device__ __forceinline__ short8 pack_afrag(floatx4 a0, floatx4 a1) {
    union { int4v i; short8 s; } u;
    u.i[0] = pkbf(a0[0], a0[1]);
    u.i[1] = pkbf(a0[2], a0[3]);
    u.i[2] = pkbf(a1[0], a1[1]);
    u.i[3] = pkbf(a1[2], a1[3]);
    return u.s;
}

__global__ __launch_bounds__(512, 2)
void nlm_kernel(const float* __restrict__ st,
                const float* __restrict__ w1,
                const float* __restrict__ b1,
                const float* __restrict__ w2,
                const float* __restrict__ b2,
                const float* __restrict__ Tp,
                float* __restrict__ out_t)
{
    const int t  = threadIdx.x;          // 0..511
    const int n0 = blockIdx.x * NPB;

    __shared__ __align__(16) float ldsS[32 * 256];   // 32 KB f32 w1 stage
    __shared__ __align__(16) short ldsB[8192];       // 16 KB bf16 frag-major
    __shared__ float4 ldsP[2][128];                  // 4 KB params dbuf
    __shared__ float  ldsO[128];                     // 0.5 KB out row
    // 53760 B total -> 3 blocks/CU (3x53760 = 161280 <= 163840)

    const int lane = t & 63;
    const int wv   = t >> 6;      // wave 0..7
    const int m    = lane & 15;   // A row / C col
    const int quad = lane >> 4;   // k-quad / C row group

    const int h      = t & 255;   // conv: owned column
    const int kh     = t >> 8;    // conv: k-half 0/1
    // fragment-major short idx = (h>>4)*512 + (k>>3)*128 + (h&15)*8 + (k&7)
    const int cvbase = ((h >> 4) * 512) + ((h & 15) * 8) + kh * 256;

    // ---------------- prologue: neuron n0 ----------------
    floatx4 av0, av1;
    {
        const int b = wv * 16 + m;
        const float* sp = st + (size_t)b * (NN * 32) + (size_t)n0 * 32 + quad * 8;
        av0 = *(const floatx4*)sp;
        av1 = *(const floatx4*)(sp + 4);
    }
    float pba = 0.f, pbb = 0.f; float2 pw2 = make_float2(0.f, 0.f);
    if (t < 128) {
        pba = b1[(size_t)n0 * 256 + t];
        pbb = b1[(size_t)n0 * 256 + 128 + t];
        pw2 = *(const float2*)(w2 + (size_t)n0 * 256 + 2 * t);
    }
    {
        const float* gW = w1 + (size_t)n0 * 8192;
        #pragma unroll
        for (int i2 = 0; i2 < 4; ++i2) {
            const int off = wv * 1024 + i2 * 256;
            gload_lds16(gW + off + lane * 4, &ldsS[off]);
        }
    }
    float bb0 = b2[n0 * 2 + 0];
    float bb1 = b2[n0 * 2 + 1];
    const float invT = 1.0f / Tp[0];
    if (t < 128) ldsP[0][t] = make_float4(pba, pbb, pw2.x, pw2.y);
    short8 afrag = pack_afrag(av0, av1);

    __syncthreads();   // prologue full drain: ldsS + ldsP[0] ready

    #pragma unroll
    for (int i = 0; i < NPB; ++i) {
        const int cur = i & 1, nxt = cur ^ 1;
        const int n = n0 + i;
        const bool hn = (i + 1 < NPB);

        // ---- 1) register prefetch for neuron n+1 (BEFORE any DMA so the
        //         compiler's waits on these are counted, not vmcnt(0)) ----
        float npa = 0.f, npb_ = 0.f; float2 npw = make_float2(0.f, 0.f);
        floatx4 nav0 = {0,0,0,0}, nav1 = {0,0,0,0};
        float nbb0 = 0.f, nbb1 = 0.f;
        if (hn) {
            const int b = wv * 16 + m;
            const float* sp = st + (size_t)b * (NN * 32) + (size_t)(n + 1) * 32 + quad * 8;
            nav0 = *(const floatx4*)sp;
            nav1 = *(const floatx4*)(sp + 4);
            if (t < 128) {
                npa  = b1[(size_t)(n + 1) * 256 + t];
                npb_ = b1[(size_t)(n + 1) * 256 + 128 + t];
                npw  = *(const float2*)(w2 + (size_t)(n + 1) * 256 + 2 * t);
            }
            nbb0 = b2[(n + 1) * 2 + 0];
            nbb1 = b2[(n + 1) * 2 + 1];
        }

        // ---- 2) conv reads from S: thread owns column h, k-half kh ----
        float w[16];
        #pragma unroll
        for (int k = 0; k < 16; ++k)
            w[k] = ldsS[(kh * 16 + k) * 256 + h];

        // ---- 3) barrier: S readers done (lgkm only; vmem stays in flight) ----
        asm volatile("s_waitcnt lgkmcnt(0)" ::: "memory");
        __builtin_amdgcn_s_barrier();
        __builtin_amdgcn_sched_barrier(0);

        // ---- 4) S is free: issue next neuron's w1 DMA into it ----
        if (hn) {
            const float* gW = w1 + (size_t)(n + 1) * 8192;
            #pragma unroll
            for (int i2 = 0; i2 < 4; ++i2) {
                const int off = wv * 1024 + i2 * 256;
                gload_lds16(gW + off + lane * 4, &ldsS[off]);
            }
        }

        // ---- 5) bf16 fragment-major writes into B; pack next afrag;
        //         stash next params (their vmem waits leave the DMA alone) ----
        #pragma unroll
        for (int q = 0; q < 2; ++q) {
            union { int4v iv; short8 s; } u;
            #pragma unroll
            for (int e = 0; e < 4; ++e)
                u.iv[e] = pkbf(w[q * 8 + 2 * e], w[q * 8 + 2 * e + 1]);
            *(short8*)&ldsB[cvbase + q * 128] = u.s;
        }
        short8 nafrag = afrag;
        if (hn) {
            nafrag = pack_afrag(nav0, nav1);
            if (t < 128) ldsP[nxt][t] = make_float4(npa, npb_, npw.x, npw.y);
        }

        // ---- 6) barrier: B (and ldsP[nxt]) visible ----
        asm volatile("s_waitcnt lgkmcnt(0)" ::: "memory");
        __builtin_amdgcn_s_barrier();
        __builtin_amdgcn_sched_barrier(0);

        // ---- 7) compute: 8 tile-pairs, fc1 bias as MFMA C-init, fc2 folded ----
        float pacc[4][2];
        #pragma unroll
        for (int r = 0; r < 4; ++r)
            pacc[r][0] = pacc[r][1] = 0.0f;

        #pragma unroll
        for (int p = 0; p < 8; ++p) {
            short8 bfA = *(short8*)&ldsB[(p * 64 + lane) * 8];
            short8 bfB = *(short8*)&ldsB[((p + 8) * 64 + lane) * 8];
            float4 prm = ldsP[cur][p * 16 + m];
            floatx4 ca = {prm.x, prm.x, prm.x, prm.x};
            floatx4 cb = {prm.y, prm.y, prm.y, prm.y};
            floatx4 xa = __builtin_amdgcn_mfma_f32_16x16x32_bf16(afrag, bfA, ca, 0, 0, 0);
            floatx4 xb = __builtin_amdgcn_mfma_f32_16x16x32_bf16(afrag, bfB, cb, 0, 0, 0);
            #pragma unroll
            for (int r = 0; r < 4; ++r) {
                float glu = xa[r] * sigmoidf_(xb[r]);
                pacc[r][0] += glu * prm.z;
                pacc[r][1] += glu * prm.w;
            }
        }

        #pragma unroll
        for (int r = 0; r < 4; ++r) {
            float s0 = pacc[r][0];
            float s1 = pacc[r][1];
            s0 += __shfl_xor(s0, 1);  s1 += __shfl_xor(s1, 1);
            s0 += __shfl_xor(s0, 2);  s1 += __shfl_xor(s1, 2);
            s0 += __shfl_xor(s0, 4);  s1 += __shfl_xor(s1, 4);
            s0 += __shfl_xor(s0, 8);  s1 += __shfl_xor(s1, 8);
            if (m == 0) {
                const int b = wv * 16 + quad * 4 + r;
                float x0 = s0 + bb0;
                float x1 = s1 + bb1;
                ldsO[b] = x0 * sigmoidf_(x1) * invT;
            }
        }

        // ---- 8) iteration-end barrier: DMA landed in S (covered by all of
        //         steps 5-7) + ldsO visible ----
        asm volatile("s_waitcnt vmcnt(0) lgkmcnt(0)" ::: "memory");
        __builtin_amdgcn_s_barrier();
        __builtin_amdgcn_sched_barrier(0);

        // ---- 9) coalesced 512B row for neuron n ----
        if (t < 128)
            out_t[(size_t)n * 128 + t] = ldsO[t];

        afrag = nafrag;
        bb0 = nbb0;
        bb1 = nbb1;
    }
}

// Transpose out_t (2048,128) -> out (128,2048). 32x32 tiles, 256 blocks.
__global__ __launch_bounds__(256)
void transpose_kernel(const float* __restrict__ out_t, float* __restrict__ out)
{
    __shared__ float tile[32][33];
    const int t    = threadIdx.x;
    const int bidx = blockIdx.x;           // 0..255
    const int n0   = (bidx & 63) * 32;     // 64 n-tiles
    const int b0   = (bidx >> 6) * 32;     // 4 b-tiles

    const int tx = t & 31;
    const int ty = t >> 5;                 // 0..7

    #pragma unroll
    for (int i = 0; i < 4; ++i) {
        const int nl = ty + i * 8;
        tile[nl][tx] = out_t[(size_t)(n0 + nl) * 128 + b0 + tx];
    }

    __syncthreads();

    #pragma unroll
    for (int i = 0; i < 4; ++i) {
        const int bl = ty + i * 8;
        out[(size_t)(b0 + bl) * NN + n0 + tx] = tile[tx][bl];
    }
}

extern "C" void kernel_launch(void* const* d_in, const int* in_sizes, int n_in,
                              void* d_out, int out_size, void* d_ws, size_t ws_size,
                              hipStream_t stream) {
    const float* st = (const float*)d_in[0];
    const float* w1 = (const float*)d_in[1];
    const float* b1 = (const float*)d_in[2];
    const float* w2 = (const float*)d_in[3];
    const float* b2 = (const float*)d_in[4];
    const float* T  = (const float*)d_in[5];
    float* out   = (float*)d_out;
    float* out_t = (float*)d_ws;    // 2048*128*4 = 1 MB scratch

    nlm_kernel<<<dim3(GRID), dim3(512), 0, stream>>>(st, w1, b1, w2, b2, T, out_t);
    transpose_kernel<<<dim3(256), dim3(256), 0, stream>>>(out_t, out);
}